// Round 16
// baseline (1063.647 us; speedup 1.0000x reference)
//
#include <hip/hip_runtime.h>

// Swin window attention, round 16: m97-structure 128x128 GEMM (r15 + 2 fixes).
// r15 bugs: (1) staging source XORed the granule swizzle that was ALREADY baked
// into the weight/x images -> double-swizzle cancel -> linear LDS -> MFMA k-granule
// mismatch for row&7 != col&7. Fix: LINEAR staging source (image carries swizzle).
// (2) attn O-writeback keyed the image swizzle to the LOCAL window row; proj's
// A-staging unswizzles by GLOBAL row (49 % 8 != 0). Fix: global-row key.
// Structure: 128^2 tile, BK=64, 4 waves x (64x64, acc 4x4), 16 ds_read_b128 :
// 32 MFMA per K-step, 6 K-steps x 2 barriers, 32 KB LDS -> 4 blocks/CU,
// zero-register global_load_lds staging.

#define NTOK 49
#define DIM 384
#define HEADS 12
#define QKV_OC 1152
#define QKV_ELEMS (1152*384)
#define PROJ_ELEMS (384*384)
#define CMB_ELEMS (64*12*49*49)
#define SCALE 0.17677669529663687f

typedef __attribute__((ext_vector_type(8))) __bf16 bf16x8;
typedef __attribute__((ext_vector_type(4))) float f32x4;

union BF8 { bf16x8 v; unsigned short u[8]; uint4 q; };

#define GLOAD_LDS16(gp, lp)                                                  \
  __builtin_amdgcn_global_load_lds(                                          \
      (const __attribute__((address_space(1))) void*)(gp),                   \
      (__attribute__((address_space(3))) void*)(lp), 16, 0, 0)

__device__ __forceinline__ unsigned short f2bf(float f) {
  union { float f; unsigned u; } x; x.f = f;
  unsigned r = x.u + 0x7fffu + ((x.u >> 16) & 1u);   // RNE
  return (unsigned short)(r >> 16);
}

__device__ __forceinline__ bf16x8 zbf8() {
  BF8 z;
  #pragma unroll
  for (int j = 0; j < 8; ++j) z.u[j] = 0;
  return z.v;
}

// ---- prep: weights -> bf16 pre-swizzled image (scale folded), cmb, bias ----
// image[c][s*8+e] = W[c][(s^(c&7))*8 + e]
__global__ void prep_kernel(const float* __restrict__ qkv_w,
                            const float* __restrict__ proj_w,
                            const float* __restrict__ bias_table,
                            const int* __restrict__ rel_idx,
                            const float* __restrict__ mask,
                            const float* __restrict__ qkv_b,
                            unsigned short* __restrict__ wq,
                            unsigned short* __restrict__ wp,
                            float* __restrict__ cmb,
                            float* __restrict__ qb2) {
  int i = blockIdx.x * 256 + threadIdx.x;
  if (i < QKV_ELEMS) {
    int c = i / 384, j = i % 384, s = j >> 3, e = j & 7;
    float v = qkv_w[c * 384 + ((s ^ (c & 7)) << 3) + e];
    if (c < 384) v *= SCALE;
    wq[i] = f2bf(v);
  } else if (i < QKV_ELEMS + PROJ_ELEMS) {
    int k = i - QKV_ELEMS;
    int c = k / 384, j = k % 384, s = j >> 3, e = j & 7;
    wp[k] = f2bf(proj_w[c * 384 + ((s ^ (c & 7)) << 3) + e]);
  } else if (i < QKV_ELEMS + PROJ_ELEMS + CMB_ELEMS) {
    int j = i - QKV_ELEMS - PROJ_ELEMS;
    int row = j % 49;
    int tok = (j / 49) % 49;
    int h   = (j / 2401) % 12;
    int wi  = j / (2401 * 12);
    cmb[j] = bias_table[rel_idx[row * 49 + tok] * HEADS + h]
           + mask[(wi * 49 + row) * 49 + tok];
  } else if (i < QKV_ELEMS + PROJ_ELEMS + CMB_ELEMS + QKV_OC) {
    int c = i - QKV_ELEMS - PROJ_ELEMS - CMB_ELEMS;
    qb2[c] = qkv_b[c] * (c < 384 ? SCALE : 1.0f);
  }
}

// ---- convx: x fp32 -> bf16 swizzled image. One granule (8 elems)/thread. ---
__global__ void convx_kernel(const float* __restrict__ x,
                             unsigned short* __restrict__ xsw, long ngran) {
  long gidx = (long)blockIdx.x * 256 + threadIdx.x;
  if (gidx >= ngran) return;
  int r = (int)(gidx / 48), s = (int)(gidx % 48);
  int ssrc = (s & 56) | ((s & 7) ^ (r & 7));
  const float* src = x + (size_t)r * 384 + ssrc * 8;
  float4 f0 = *(const float4*)src;
  float4 f1 = *(const float4*)(src + 4);
  BF8 t;
  t.u[0] = f2bf(f0.x); t.u[1] = f2bf(f0.y); t.u[2] = f2bf(f0.z); t.u[3] = f2bf(f0.w);
  t.u[4] = f2bf(f1.x); t.u[5] = f2bf(f1.y); t.u[6] = f2bf(f1.z); t.u[7] = f2bf(f1.w);
  *(uint4*)(xsw + (size_t)r * 384 + s * 8) = t.q;
}

// ---- gemm128: C[M][NP*128] = A[M][384] @ W[NP*128][384]^T + bias ----------
// 128x128 tile, BK=64, 4 waves (2x2) each 64x64 / acc 4x4. A and W are
// pre-swizzled images -> staging uses LINEAR source offsets; the LDS read
// XOR (granule ^ (li&7)) undoes the image swizzle. 2 barriers/K-step.
template<int BF16OUT>
__global__ __launch_bounds__(256, 4) void gemm128(
    const unsigned short* __restrict__ Asw, const unsigned short* __restrict__ Wsw,
    const float* __restrict__ bias, void* __restrict__ Cout,
    int Mrows, int Ntot, int NRB) {
  __shared__ alignas(16) unsigned short As[128 * 64];   // 16 KB
  __shared__ alignas(16) unsigned short Bs[128 * 64];   // 16 KB
  const int bid = blockIdx.x;
  const int rowb = bid % NRB, colp = bid / NRB;
  const int tb = rowb * 128, nb = colp * 128;
  const int tid = threadIdx.x;
  const int wave = tid >> 6, lane = tid & 63, g = lane >> 4, li = lane & 15;
  const int wr = wave >> 1, wc = wave & 1;
  const int chbase = wave * 256 + lane;

  f32x4 acc[4][4];
  #pragma unroll
  for (int m = 0; m < 4; ++m)
    #pragma unroll
    for (int n = 0; n < 4; ++n) acc[m][n] = (f32x4){0.f, 0.f, 0.f, 0.f};

  #pragma unroll 1
  for (int step = 0; step < 6; ++step) {
    const int k0 = step * 64;
    if (step) __syncthreads();            // everyone done reading prev tiles
    // stage A tile [128 rows][64 k] and B tile [128 cols][64 k].
    // LINEAR source: the image already carries the granule swizzle.
    #pragma unroll
    for (int i = 0; i < 4; ++i) {
      int ch = chbase + i * 64;           // 0..1023
      int r = ch >> 3, s = ch & 7;
      GLOAD_LDS16(Asw + (size_t)(tb + r) * 384 + k0 + s * 8,
                  (unsigned short*)As + ch * 8);
    }
    #pragma unroll
    for (int i = 0; i < 4; ++i) {
      int ch = chbase + i * 64;
      int c = ch >> 3, s = ch & 7;
      GLOAD_LDS16(Wsw + (size_t)(nb + c) * 384 + k0 + s * 8,
                  (unsigned short*)Bs + ch * 8);
    }
    __syncthreads();                      // vmcnt(0) drain -> tiles resident

    #pragma unroll
    for (int kk = 0; kk < 2; ++kk) {
      const int goff = ((kk * 4 + g) ^ (li & 7)) << 3;
      bf16x8 a0 = *(const bf16x8*)&As[(wr * 64 +  0 + li) * 64 + goff];
      bf16x8 a1 = *(const bf16x8*)&As[(wr * 64 + 16 + li) * 64 + goff];
      bf16x8 a2 = *(const bf16x8*)&As[(wr * 64 + 32 + li) * 64 + goff];
      bf16x8 a3 = *(const bf16x8*)&As[(wr * 64 + 48 + li) * 64 + goff];
      bf16x8 b0 = *(const bf16x8*)&Bs[(wc * 64 +  0 + li) * 64 + goff];
      bf16x8 b1 = *(const bf16x8*)&Bs[(wc * 64 + 16 + li) * 64 + goff];
      bf16x8 b2 = *(const bf16x8*)&Bs[(wc * 64 + 32 + li) * 64 + goff];
      bf16x8 b3 = *(const bf16x8*)&Bs[(wc * 64 + 48 + li) * 64 + goff];
      acc[0][0] = __builtin_amdgcn_mfma_f32_16x16x32_bf16(a0, b0, acc[0][0], 0, 0, 0);
      acc[0][1] = __builtin_amdgcn_mfma_f32_16x16x32_bf16(a0, b1, acc[0][1], 0, 0, 0);
      acc[0][2] = __builtin_amdgcn_mfma_f32_16x16x32_bf16(a0, b2, acc[0][2], 0, 0, 0);
      acc[0][3] = __builtin_amdgcn_mfma_f32_16x16x32_bf16(a0, b3, acc[0][3], 0, 0, 0);
      acc[1][0] = __builtin_amdgcn_mfma_f32_16x16x32_bf16(a1, b0, acc[1][0], 0, 0, 0);
      acc[1][1] = __builtin_amdgcn_mfma_f32_16x16x32_bf16(a1, b1, acc[1][1], 0, 0, 0);
      acc[1][2] = __builtin_amdgcn_mfma_f32_16x16x32_bf16(a1, b2, acc[1][2], 0, 0, 0);
      acc[1][3] = __builtin_amdgcn_mfma_f32_16x16x32_bf16(a1, b3, acc[1][3], 0, 0, 0);
      acc[2][0] = __builtin_amdgcn_mfma_f32_16x16x32_bf16(a2, b0, acc[2][0], 0, 0, 0);
      acc[2][1] = __builtin_amdgcn_mfma_f32_16x16x32_bf16(a2, b1, acc[2][1], 0, 0, 0);
      acc[2][2] = __builtin_amdgcn_mfma_f32_16x16x32_bf16(a2, b2, acc[2][2], 0, 0, 0);
      acc[2][3] = __builtin_amdgcn_mfma_f32_16x16x32_bf16(a2, b3, acc[2][3], 0, 0, 0);
      acc[3][0] = __builtin_amdgcn_mfma_f32_16x16x32_bf16(a3, b0, acc[3][0], 0, 0, 0);
      acc[3][1] = __builtin_amdgcn_mfma_f32_16x16x32_bf16(a3, b1, acc[3][1], 0, 0, 0);
      acc[3][2] = __builtin_amdgcn_mfma_f32_16x16x32_bf16(a3, b2, acc[3][2], 0, 0, 0);
      acc[3][3] = __builtin_amdgcn_mfma_f32_16x16x32_bf16(a3, b3, acc[3][3], 0, 0, 0);
    }
  }

  // epilogue
  #pragma unroll
  for (int n = 0; n < 4; ++n) {
    int col = nb + wc * 64 + n * 16 + li;
    float bv = bias[col];
    #pragma unroll
    for (int m = 0; m < 4; ++m) {
      #pragma unroll
      for (int r4 = 0; r4 < 4; ++r4) {
        int row = tb + wr * 64 + m * 16 + g * 4 + r4;
        if (row < Mrows) {
          float v = acc[m][n][r4] + bv;
          if (BF16OUT) ((unsigned short*)Cout)[(size_t)row * Ntot + col] = f2bf(v);
          else         ((float*)Cout)[(size_t)row * Ntot + col] = v;
        }
      }
    }
  }
}

// ---- attn: per-window; q direct from qkv; K/V in LDS; O -> swizzled image --
#define AT_K 0                   // [49][128] swizzled K chunk
#define AT_V (49*128)            // [49][138] plain V chunk (bank-spread)
#define AT_ELEMS (AT_V + 49*138)

__global__ __launch_bounds__(512, 6) void attn_kernel(
    const unsigned short* __restrict__ qkv,   // [WB*49][1152] linear
    const float* __restrict__ cmb,
    unsigned short* __restrict__ Obuf,        // [WB*49][384] swizzled image
    int wb0) {
  __shared__ unsigned short lds[AT_ELEMS];
  const int tid  = threadIdx.x;
  const int wave = tid >> 6, lane = tid & 63;
  const int g = lane >> 4, li = lane & 15;
  const int relw = blockIdx.x;
  const int wi = (wb0 + relw) & 63;
  const size_t rowbase = (size_t)relw * 49;
  const int mgrp = wave >> 1, ng = wave & 1;
  const int arow = mgrp * 16 + li;

  #pragma unroll 1
  for (int c = 0; c < 3; ++c) {
    if (c) __syncthreads();
    #pragma unroll
    for (int it = 0; it < 2; ++it) {
      int gidx = it * 512 + tid;
      if (gidx < 784) {
        int row = gidx >> 4, gc = gidx & 15;
        bf16x8 v = *(const bf16x8*)(qkv + (rowbase + row) * 1152 + 384 + c * 128 + gc * 8);
        *(bf16x8*)&lds[AT_K + row * 128 + ((gc ^ (row & 7)) << 3)] = v;
      }
    }
    #pragma unroll
    for (int it = 0; it < 2; ++it) {
      int gidx = it * 512 + tid;
      if (gidx < 784) {
        int row = gidx >> 4, gc = gidx & 15;
        BF8 v;
        v.q = *(const uint4*)(qkv + (rowbase + row) * 1152 + 768 + c * 128 + gc * 8);
        int e = AT_V + row * 138 + gc * 8;
        *(unsigned*)&lds[e]     = v.q.x;
        *(unsigned*)&lds[e + 2] = v.q.y;
        *(unsigned*)&lds[e + 4] = v.q.z;
        *(unsigned*)&lds[e + 6] = v.q.w;
      }
    }
    __syncthreads();

    #pragma unroll 1
    for (int b = 0; b < 2; ++b) {
      const int hh = ng * 2 + b;
      const int h  = c * 4 + hh;

      bf16x8 qa = (arow < NTOK)
          ? *(const bf16x8*)(qkv + (rowbase + arow) * 1152 + h * 32 + g * 8)
          : zbf8();

      f32x4 sv[4];
      #pragma unroll
      for (int nt = 0; nt < 4; ++nt) {
        int tok = nt * 16 + li;
        bf16x8 kf = (tok < NTOK)
            ? *(const bf16x8*)&lds[AT_K + tok * 128 + (((hh * 4 + g) ^ (tok & 7)) << 3)]
            : zbf8();
        f32x4 z4 = (f32x4){0.f, 0.f, 0.f, 0.f};
        sv[nt] = __builtin_amdgcn_mfma_f32_16x16x32_bf16(kf, qa, z4, 0, 0, 0);
      }

      const float* cb = cmb + (size_t)(wi * HEADS + h) * (NTOK * NTOK);
      #pragma unroll
      for (int nt = 0; nt < 4; ++nt) {
        #pragma unroll
        for (int r4 = 0; r4 < 4; ++r4) {
          int tok = nt * 16 + g * 4 + r4;
          float v;
          if (tok < NTOK) {
            v = sv[nt][r4];
            if (arow < NTOK) v += cb[tok * NTOK + arow];
          } else {
            v = -1e30f;
          }
          sv[nt][r4] = v;
        }
      }

      float m = -1e30f;
      #pragma unroll
      for (int nt = 0; nt < 4; ++nt)
        #pragma unroll
        for (int r4 = 0; r4 < 4; ++r4) m = fmaxf(m, sv[nt][r4]);
      m = fmaxf(m, __shfl_xor(m, 16));
      m = fmaxf(m, __shfl_xor(m, 32));
      float s = 0.f;
      #pragma unroll
      for (int nt = 0; nt < 4; ++nt)
        #pragma unroll
        for (int r4 = 0; r4 < 4; ++r4) {
          float e = __expf(sv[nt][r4] - m);
          sv[nt][r4] = e;
          s += e;
        }
      s += __shfl_xor(s, 16);
      s += __shfl_xor(s, 32);
      float inv = 1.f / s;
      #pragma unroll
      for (int nt = 0; nt < 4; ++nt)
        #pragma unroll
        for (int r4 = 0; r4 < 4; ++r4) sv[nt][r4] *= inv;

      bf16x8 pa[2];
      #pragma unroll
      for (int k2 = 0; k2 < 2; ++k2) {
        BF8 pf;
        #pragma unroll
        for (int j = 0; j < 8; ++j) {
          int srcLane = (((g * 2 + (j >> 2)) & 3) << 4) | li;
          float v0 = __shfl(sv[k2 * 2][j & 3], srcLane);
          float v1 = __shfl(sv[k2 * 2 + 1][j & 3], srcLane);
          pf.u[j] = f2bf((g >= 2) ? v1 : v0);
        }
        pa[k2] = pf.v;
      }

      f32x4 oa[2];
      oa[0] = (f32x4){0.f, 0.f, 0.f, 0.f};
      oa[1] = (f32x4){0.f, 0.f, 0.f, 0.f};
      #pragma unroll
      for (int k2 = 0; k2 < 2; ++k2) {
        #pragma unroll
        for (int nt2 = 0; nt2 < 2; ++nt2) {
          BF8 vb;
          int ch = hh * 32 + nt2 * 16 + li;
          #pragma unroll
          for (int j = 0; j < 8; ++j) {
            int tok = k2 * 32 + g * 8 + j;
            vb.u[j] = (tok < NTOK) ? lds[AT_V + tok * 138 + ch] : (unsigned short)0;
          }
          oa[nt2] = __builtin_amdgcn_mfma_f32_16x16x32_bf16(pa[k2], vb.v, oa[nt2], 0, 0, 0);
        }
      }

      // O -> swizzled image, keyed to the GLOBAL row (proj unswizzles by it)
      #pragma unroll
      for (int nt2 = 0; nt2 < 2; ++nt2) {
        int colb = h * 32 + nt2 * 16 + li;
        int gran = colb >> 3;
        #pragma unroll
        for (int r4 = 0; r4 < 4; ++r4) {
          int row = mgrp * 16 + g * 4 + r4;
          if (row < NTOK) {
            int grow = (int)(rowbase) + row;
            int col2 = (((gran & 56) | ((gran & 7) ^ (grow & 7))) << 3) | (colb & 7);
            Obuf[(size_t)grow * 384 + col2] = f2bf(oa[nt2][r4]);
          }
        }
      }
    }
  }
}

extern "C" void kernel_launch(void* const* d_in, const int* in_sizes, int n_in,
                              void* d_out, int out_size, void* d_ws, size_t ws_size,
                              hipStream_t stream) {
  (void)in_sizes; (void)n_in; (void)out_size;
  const float* x          = (const float*)d_in[0];
  const float* mask       = (const float*)d_in[1];
  const float* qkv_w      = (const float*)d_in[2];
  const float* qkv_b      = (const float*)d_in[3];
  const float* proj_w     = (const float*)d_in[4];
  const float* proj_b     = (const float*)d_in[5];
  const float* bias_table = (const float*)d_in[6];
  const int*   rel_idx    = (const int*)d_in[7];
  float* out = (float*)d_out;

  char* ws = (char*)d_ws;
  size_t off = 0;
  unsigned short* wq  = (unsigned short*)(ws + off); off += (size_t)QKV_ELEMS * 2;
  unsigned short* wp  = (unsigned short*)(ws + off); off += (size_t)PROJ_ELEMS * 2;
  float*          qb2 = (float*)(ws + off);          off += (size_t)QKV_OC * 4;
  float*          cmb = (float*)(ws + off);          off += (size_t)CMB_ELEMS * 4;
  const size_t fixed = off;

  // batch size: WB=2048 -> M=100352=784x128 exact; qkv grid 7056 blocks
  const int cands[7] = {2048, 4096, 1024, 512, 256, 128, 64};
  int WB = 64;
  for (int ci = 0; ci < 7; ++ci) {
    int mrows = cands[ci] * 49;
    int mpad = ((mrows + 127) / 128) * 128;
    size_t need = fixed + (size_t)mpad * 384 * 2 + (size_t)mrows * 1152 * 2;
    if (need <= ws_size) { WB = cands[ci]; break; }
  }
  const int Mrows = WB * 49;
  const int Mpad  = ((Mrows + 127) / 128) * 128;
  const int NRB   = Mpad / 128;
  unsigned short* xsw = (unsigned short*)(ws + fixed);          // x image / O image
  unsigned short* qkv = xsw + (size_t)Mpad * 384;

  const int prep_total = QKV_ELEMS + PROJ_ELEMS + CMB_ELEMS + QKV_OC;
  prep_kernel<<<(prep_total + 255) / 256, 256, 0, stream>>>(
      qkv_w, proj_w, bias_table, rel_idx, mask, qkv_b, wq, wp, cmb, qb2);

  const int NB = 4096 / WB;
  const long ngran = (long)Mrows * 48;
  for (int b = 0; b < NB; ++b) {
    convx_kernel<<<(int)((ngran + 255) / 256), 256, 0, stream>>>(
        x + (size_t)b * Mrows * 384, xsw, ngran);
    gemm128<1><<<NRB * 9, 256, 0, stream>>>(xsw, wq, qb2, (void*)qkv,
                                            Mrows, 1152, NRB);
    attn_kernel<<<WB, 512, 0, stream>>>(qkv, cmb, xsw, b * WB);
    gemm128<0><<<NRB * 3, 256, 0, stream>>>(xsw, wp, proj_b,
        (void*)(out + (size_t)b * Mrows * 384), Mrows, 384, NRB);
  }
}

// Round 17
// 1050.227 us; speedup vs baseline: 1.0128x; 1.0128x over previous
//
#include <hip/hip_runtime.h>

// Swin window attention, round 17: r16 + GEMM block-order swizzle.
// r16 counters: qkv gemm FETCH 334 MB (ideal ~78) at 3.0 TB/s -- rowb-fastest
// dispatch re-fetched the A-tile ~9x (once per col-panel, scattered across
// XCDs). Single change: bijective XCD-chunk swizzle (m204) + colp-FASTEST
// decomposition, so the 9 blocks sharing an A-tile are consecutive within one
// XCD -> A read once into that XCD's L2, re-served 9x. Everything else
// identical to r16 (which passed, absmax 1.95e-3).

#define NTOK 49
#define DIM 384
#define HEADS 12
#define QKV_OC 1152
#define QKV_ELEMS (1152*384)
#define PROJ_ELEMS (384*384)
#define CMB_ELEMS (64*12*49*49)
#define SCALE 0.17677669529663687f

typedef __attribute__((ext_vector_type(8))) __bf16 bf16x8;
typedef __attribute__((ext_vector_type(4))) float f32x4;

union BF8 { bf16x8 v; unsigned short u[8]; uint4 q; };

#define GLOAD_LDS16(gp, lp)                                                  \
  __builtin_amdgcn_global_load_lds(                                          \
      (const __attribute__((address_space(1))) void*)(gp),                   \
      (__attribute__((address_space(3))) void*)(lp), 16, 0, 0)

__device__ __forceinline__ unsigned short f2bf(float f) {
  union { float f; unsigned u; } x; x.f = f;
  unsigned r = x.u + 0x7fffu + ((x.u >> 16) & 1u);   // RNE
  return (unsigned short)(r >> 16);
}

__device__ __forceinline__ bf16x8 zbf8() {
  BF8 z;
  #pragma unroll
  for (int j = 0; j < 8; ++j) z.u[j] = 0;
  return z.v;
}

// ---- prep: weights -> bf16 pre-swizzled image (scale folded), cmb, bias ----
// image[c][s*8+e] = W[c][(s^(c&7))*8 + e]
__global__ void prep_kernel(const float* __restrict__ qkv_w,
                            const float* __restrict__ proj_w,
                            const float* __restrict__ bias_table,
                            const int* __restrict__ rel_idx,
                            const float* __restrict__ mask,
                            const float* __restrict__ qkv_b,
                            unsigned short* __restrict__ wq,
                            unsigned short* __restrict__ wp,
                            float* __restrict__ cmb,
                            float* __restrict__ qb2) {
  int i = blockIdx.x * 256 + threadIdx.x;
  if (i < QKV_ELEMS) {
    int c = i / 384, j = i % 384, s = j >> 3, e = j & 7;
    float v = qkv_w[c * 384 + ((s ^ (c & 7)) << 3) + e];
    if (c < 384) v *= SCALE;
    wq[i] = f2bf(v);
  } else if (i < QKV_ELEMS + PROJ_ELEMS) {
    int k = i - QKV_ELEMS;
    int c = k / 384, j = k % 384, s = j >> 3, e = j & 7;
    wp[k] = f2bf(proj_w[c * 384 + ((s ^ (c & 7)) << 3) + e]);
  } else if (i < QKV_ELEMS + PROJ_ELEMS + CMB_ELEMS) {
    int j = i - QKV_ELEMS - PROJ_ELEMS;
    int row = j % 49;
    int tok = (j / 49) % 49;
    int h   = (j / 2401) % 12;
    int wi  = j / (2401 * 12);
    cmb[j] = bias_table[rel_idx[row * 49 + tok] * HEADS + h]
           + mask[(wi * 49 + row) * 49 + tok];
  } else if (i < QKV_ELEMS + PROJ_ELEMS + CMB_ELEMS + QKV_OC) {
    int c = i - QKV_ELEMS - PROJ_ELEMS - CMB_ELEMS;
    qb2[c] = qkv_b[c] * (c < 384 ? SCALE : 1.0f);
  }
}

// ---- convx: x fp32 -> bf16 swizzled image. One granule (8 elems)/thread. ---
__global__ void convx_kernel(const float* __restrict__ x,
                             unsigned short* __restrict__ xsw, long ngran) {
  long gidx = (long)blockIdx.x * 256 + threadIdx.x;
  if (gidx >= ngran) return;
  int r = (int)(gidx / 48), s = (int)(gidx % 48);
  int ssrc = (s & 56) | ((s & 7) ^ (r & 7));
  const float* src = x + (size_t)r * 384 + ssrc * 8;
  float4 f0 = *(const float4*)src;
  float4 f1 = *(const float4*)(src + 4);
  BF8 t;
  t.u[0] = f2bf(f0.x); t.u[1] = f2bf(f0.y); t.u[2] = f2bf(f0.z); t.u[3] = f2bf(f0.w);
  t.u[4] = f2bf(f1.x); t.u[5] = f2bf(f1.y); t.u[6] = f2bf(f1.z); t.u[7] = f2bf(f1.w);
  *(uint4*)(xsw + (size_t)r * 384 + s * 8) = t.q;
}

// ---- gemm128: C[M][ncp*128] = A[M][384] @ W[ncp*128][384]^T + bias --------
// 128x128 tile, BK=64, 4 waves (2x2) each 64x64 / acc 4x4. Pre-swizzled
// images -> linear staging source; LDS read XOR undoes the swizzle.
// Block order: XCD-chunked (m204) + colp-FASTEST for A-tile L2 reuse.
template<int BF16OUT>
__global__ __launch_bounds__(256, 4) void gemm128(
    const unsigned short* __restrict__ Asw, const unsigned short* __restrict__ Wsw,
    const float* __restrict__ bias, void* __restrict__ Cout,
    int Mrows, int Ntot, int ncp) {
  __shared__ alignas(16) unsigned short As[128 * 64];   // 16 KB
  __shared__ alignas(16) unsigned short Bs[128 * 64];   // 16 KB
  // bijective XCD-chunk swizzle: consecutive wgid stay on one XCD
  const int nwg = gridDim.x;
  const int bid = blockIdx.x;
  const int q8 = nwg >> 3, r8 = nwg & 7;
  const int xcd = bid & 7, lin = bid >> 3;
  const int wgid = (xcd < r8 ? xcd * (q8 + 1) : r8 * (q8 + 1) + (xcd - r8) * q8) + lin;
  const int colp = wgid % ncp, rowb = wgid / ncp;   // colp fastest: A reuse
  const int tb = rowb * 128, nb = colp * 128;
  const int tid = threadIdx.x;
  const int wave = tid >> 6, lane = tid & 63, g = lane >> 4, li = lane & 15;
  const int wr = wave >> 1, wc = wave & 1;
  const int chbase = wave * 256 + lane;

  f32x4 acc[4][4];
  #pragma unroll
  for (int m = 0; m < 4; ++m)
    #pragma unroll
    for (int n = 0; n < 4; ++n) acc[m][n] = (f32x4){0.f, 0.f, 0.f, 0.f};

  #pragma unroll 1
  for (int step = 0; step < 6; ++step) {
    const int k0 = step * 64;
    if (step) __syncthreads();            // everyone done reading prev tiles
    #pragma unroll
    for (int i = 0; i < 4; ++i) {
      int ch = chbase + i * 64;           // 0..1023
      int r = ch >> 3, s = ch & 7;
      GLOAD_LDS16(Asw + (size_t)(tb + r) * 384 + k0 + s * 8,
                  (unsigned short*)As + ch * 8);
    }
    #pragma unroll
    for (int i = 0; i < 4; ++i) {
      int ch = chbase + i * 64;
      int c = ch >> 3, s = ch & 7;
      GLOAD_LDS16(Wsw + (size_t)(nb + c) * 384 + k0 + s * 8,
                  (unsigned short*)Bs + ch * 8);
    }
    __syncthreads();                      // vmcnt(0) drain -> tiles resident

    #pragma unroll
    for (int kk = 0; kk < 2; ++kk) {
      const int goff = ((kk * 4 + g) ^ (li & 7)) << 3;
      bf16x8 a0 = *(const bf16x8*)&As[(wr * 64 +  0 + li) * 64 + goff];
      bf16x8 a1 = *(const bf16x8*)&As[(wr * 64 + 16 + li) * 64 + goff];
      bf16x8 a2 = *(const bf16x8*)&As[(wr * 64 + 32 + li) * 64 + goff];
      bf16x8 a3 = *(const bf16x8*)&As[(wr * 64 + 48 + li) * 64 + goff];
      bf16x8 b0 = *(const bf16x8*)&Bs[(wc * 64 +  0 + li) * 64 + goff];
      bf16x8 b1 = *(const bf16x8*)&Bs[(wc * 64 + 16 + li) * 64 + goff];
      bf16x8 b2 = *(const bf16x8*)&Bs[(wc * 64 + 32 + li) * 64 + goff];
      bf16x8 b3 = *(const bf16x8*)&Bs[(wc * 64 + 48 + li) * 64 + goff];
      acc[0][0] = __builtin_amdgcn_mfma_f32_16x16x32_bf16(a0, b0, acc[0][0], 0, 0, 0);
      acc[0][1] = __builtin_amdgcn_mfma_f32_16x16x32_bf16(a0, b1, acc[0][1], 0, 0, 0);
      acc[0][2] = __builtin_amdgcn_mfma_f32_16x16x32_bf16(a0, b2, acc[0][2], 0, 0, 0);
      acc[0][3] = __builtin_amdgcn_mfma_f32_16x16x32_bf16(a0, b3, acc[0][3], 0, 0, 0);
      acc[1][0] = __builtin_amdgcn_mfma_f32_16x16x32_bf16(a1, b0, acc[1][0], 0, 0, 0);
      acc[1][1] = __builtin_amdgcn_mfma_f32_16x16x32_bf16(a1, b1, acc[1][1], 0, 0, 0);
      acc[1][2] = __builtin_amdgcn_mfma_f32_16x16x32_bf16(a1, b2, acc[1][2], 0, 0, 0);
      acc[1][3] = __builtin_amdgcn_mfma_f32_16x16x32_bf16(a1, b3, acc[1][3], 0, 0, 0);
      acc[2][0] = __builtin_amdgcn_mfma_f32_16x16x32_bf16(a2, b0, acc[2][0], 0, 0, 0);
      acc[2][1] = __builtin_amdgcn_mfma_f32_16x16x32_bf16(a2, b1, acc[2][1], 0, 0, 0);
      acc[2][2] = __builtin_amdgcn_mfma_f32_16x16x32_bf16(a2, b2, acc[2][2], 0, 0, 0);
      acc[2][3] = __builtin_amdgcn_mfma_f32_16x16x32_bf16(a2, b3, acc[2][3], 0, 0, 0);
      acc[3][0] = __builtin_amdgcn_mfma_f32_16x16x32_bf16(a3, b0, acc[3][0], 0, 0, 0);
      acc[3][1] = __builtin_amdgcn_mfma_f32_16x16x32_bf16(a3, b1, acc[3][1], 0, 0, 0);
      acc[3][2] = __builtin_amdgcn_mfma_f32_16x16x32_bf16(a3, b2, acc[3][2], 0, 0, 0);
      acc[3][3] = __builtin_amdgcn_mfma_f32_16x16x32_bf16(a3, b3, acc[3][3], 0, 0, 0);
    }
  }

  // epilogue
  #pragma unroll
  for (int n = 0; n < 4; ++n) {
    int col = nb + wc * 64 + n * 16 + li;
    float bv = bias[col];
    #pragma unroll
    for (int m = 0; m < 4; ++m) {
      #pragma unroll
      for (int r4 = 0; r4 < 4; ++r4) {
        int row = tb + wr * 64 + m * 16 + g * 4 + r4;
        if (row < Mrows) {
          float v = acc[m][n][r4] + bv;
          if (BF16OUT) ((unsigned short*)Cout)[(size_t)row * Ntot + col] = f2bf(v);
          else         ((float*)Cout)[(size_t)row * Ntot + col] = v;
        }
      }
    }
  }
}

// ---- attn: per-window; q direct from qkv; K/V in LDS; O -> swizzled image --
#define AT_K 0                   // [49][128] swizzled K chunk
#define AT_V (49*128)            // [49][138] plain V chunk (bank-spread)
#define AT_ELEMS (AT_V + 49*138)

__global__ __launch_bounds__(512, 6) void attn_kernel(
    const unsigned short* __restrict__ qkv,   // [WB*49][1152] linear
    const float* __restrict__ cmb,
    unsigned short* __restrict__ Obuf,        // [WB*49][384] swizzled image
    int wb0) {
  __shared__ unsigned short lds[AT_ELEMS];
  const int tid  = threadIdx.x;
  const int wave = tid >> 6, lane = tid & 63;
  const int g = lane >> 4, li = lane & 15;
  const int relw = blockIdx.x;
  const int wi = (wb0 + relw) & 63;
  const size_t rowbase = (size_t)relw * 49;
  const int mgrp = wave >> 1, ng = wave & 1;
  const int arow = mgrp * 16 + li;

  #pragma unroll 1
  for (int c = 0; c < 3; ++c) {
    if (c) __syncthreads();
    #pragma unroll
    for (int it = 0; it < 2; ++it) {
      int gidx = it * 512 + tid;
      if (gidx < 784) {
        int row = gidx >> 4, gc = gidx & 15;
        bf16x8 v = *(const bf16x8*)(qkv + (rowbase + row) * 1152 + 384 + c * 128 + gc * 8);
        *(bf16x8*)&lds[AT_K + row * 128 + ((gc ^ (row & 7)) << 3)] = v;
      }
    }
    #pragma unroll
    for (int it = 0; it < 2; ++it) {
      int gidx = it * 512 + tid;
      if (gidx < 784) {
        int row = gidx >> 4, gc = gidx & 15;
        BF8 v;
        v.q = *(const uint4*)(qkv + (rowbase + row) * 1152 + 768 + c * 128 + gc * 8);
        int e = AT_V + row * 138 + gc * 8;
        *(unsigned*)&lds[e]     = v.q.x;
        *(unsigned*)&lds[e + 2] = v.q.y;
        *(unsigned*)&lds[e + 4] = v.q.z;
        *(unsigned*)&lds[e + 6] = v.q.w;
      }
    }
    __syncthreads();

    #pragma unroll 1
    for (int b = 0; b < 2; ++b) {
      const int hh = ng * 2 + b;
      const int h  = c * 4 + hh;

      bf16x8 qa = (arow < NTOK)
          ? *(const bf16x8*)(qkv + (rowbase + arow) * 1152 + h * 32 + g * 8)
          : zbf8();

      f32x4 sv[4];
      #pragma unroll
      for (int nt = 0; nt < 4; ++nt) {
        int tok = nt * 16 + li;
        bf16x8 kf = (tok < NTOK)
            ? *(const bf16x8*)&lds[AT_K + tok * 128 + (((hh * 4 + g) ^ (tok & 7)) << 3)]
            : zbf8();
        f32x4 z4 = (f32x4){0.f, 0.f, 0.f, 0.f};
        sv[nt] = __builtin_amdgcn_mfma_f32_16x16x32_bf16(kf, qa, z4, 0, 0, 0);
      }

      const float* cb = cmb + (size_t)(wi * HEADS + h) * (NTOK * NTOK);
      #pragma unroll
      for (int nt = 0; nt < 4; ++nt) {
        #pragma unroll
        for (int r4 = 0; r4 < 4; ++r4) {
          int tok = nt * 16 + g * 4 + r4;
          float v;
          if (tok < NTOK) {
            v = sv[nt][r4];
            if (arow < NTOK) v += cb[tok * NTOK + arow];
          } else {
            v = -1e30f;
          }
          sv[nt][r4] = v;
        }
      }

      float m = -1e30f;
      #pragma unroll
      for (int nt = 0; nt < 4; ++nt)
        #pragma unroll
        for (int r4 = 0; r4 < 4; ++r4) m = fmaxf(m, sv[nt][r4]);
      m = fmaxf(m, __shfl_xor(m, 16));
      m = fmaxf(m, __shfl_xor(m, 32));
      float s = 0.f;
      #pragma unroll
      for (int nt = 0; nt < 4; ++nt)
        #pragma unroll
        for (int r4 = 0; r4 < 4; ++r4) {
          float e = __expf(sv[nt][r4] - m);
          sv[nt][r4] = e;
          s += e;
        }
      s += __shfl_xor(s, 16);
      s += __shfl_xor(s, 32);
      float inv = 1.f / s;
      #pragma unroll
      for (int nt = 0; nt < 4; ++nt)
        #pragma unroll
        for (int r4 = 0; r4 < 4; ++r4) sv[nt][r4] *= inv;

      bf16x8 pa[2];
      #pragma unroll
      for (int k2 = 0; k2 < 2; ++k2) {
        BF8 pf;
        #pragma unroll
        for (int j = 0; j < 8; ++j) {
          int srcLane = (((g * 2 + (j >> 2)) & 3) << 4) | li;
          float v0 = __shfl(sv[k2 * 2][j & 3], srcLane);
          float v1 = __shfl(sv[k2 * 2 + 1][j & 3], srcLane);
          pf.u[j] = f2bf((g >= 2) ? v1 : v0);
        }
        pa[k2] = pf.v;
      }

      f32x4 oa[2];
      oa[0] = (f32x4){0.f, 0.f, 0.f, 0.f};
      oa[1] = (f32x4){0.f, 0.f, 0.f, 0.f};
      #pragma unroll
      for (int k2 = 0; k2 < 2; ++k2) {
        #pragma unroll
        for (int nt2 = 0; nt2 < 2; ++nt2) {
          BF8 vb;
          int ch = hh * 32 + nt2 * 16 + li;
          #pragma unroll
          for (int j = 0; j < 8; ++j) {
            int tok = k2 * 32 + g * 8 + j;
            vb.u[j] = (tok < NTOK) ? lds[AT_V + tok * 138 + ch] : (unsigned short)0;
          }
          oa[nt2] = __builtin_amdgcn_mfma_f32_16x16x32_bf16(pa[k2], vb.v, oa[nt2], 0, 0, 0);
        }
      }

      // O -> swizzled image, keyed to the GLOBAL row
      #pragma unroll
      for (int nt2 = 0; nt2 < 2; ++nt2) {
        int colb = h * 32 + nt2 * 16 + li;
        int gran = colb >> 3;
        #pragma unroll
        for (int r4 = 0; r4 < 4; ++r4) {
          int row = mgrp * 16 + g * 4 + r4;
          if (row < NTOK) {
            int grow = (int)(rowbase) + row;
            int col2 = (((gran & 56) | ((gran & 7) ^ (grow & 7))) << 3) | (colb & 7);
            Obuf[(size_t)grow * 384 + col2] = f2bf(oa[nt2][r4]);
          }
        }
      }
    }
  }
}

extern "C" void kernel_launch(void* const* d_in, const int* in_sizes, int n_in,
                              void* d_out, int out_size, void* d_ws, size_t ws_size,
                              hipStream_t stream) {
  (void)in_sizes; (void)n_in; (void)out_size;
  const float* x          = (const float*)d_in[0];
  const float* mask       = (const float*)d_in[1];
  const float* qkv_w      = (const float*)d_in[2];
  const float* qkv_b      = (const float*)d_in[3];
  const float* proj_w     = (const float*)d_in[4];
  const float* proj_b     = (const float*)d_in[5];
  const float* bias_table = (const float*)d_in[6];
  const int*   rel_idx    = (const int*)d_in[7];
  float* out = (float*)d_out;

  char* ws = (char*)d_ws;
  size_t off = 0;
  unsigned short* wq  = (unsigned short*)(ws + off); off += (size_t)QKV_ELEMS * 2;
  unsigned short* wp  = (unsigned short*)(ws + off); off += (size_t)PROJ_ELEMS * 2;
  float*          qb2 = (float*)(ws + off);          off += (size_t)QKV_OC * 4;
  float*          cmb = (float*)(ws + off);          off += (size_t)CMB_ELEMS * 4;
  const size_t fixed = off;

  // batch size: WB=2048 -> M=100352=784x128 exact; qkv grid 7056 blocks
  const int cands[7] = {2048, 4096, 1024, 512, 256, 128, 64};
  int WB = 64;
  for (int ci = 0; ci < 7; ++ci) {
    int mrows = cands[ci] * 49;
    int mpad = ((mrows + 127) / 128) * 128;
    size_t need = fixed + (size_t)mpad * 384 * 2 + (size_t)mrows * 1152 * 2;
    if (need <= ws_size) { WB = cands[ci]; break; }
  }
  const int Mrows = WB * 49;
  const int Mpad  = ((Mrows + 127) / 128) * 128;
  const int NRB   = Mpad / 128;
  unsigned short* xsw = (unsigned short*)(ws + fixed);          // x image / O image
  unsigned short* qkv = xsw + (size_t)Mpad * 384;

  const int prep_total = QKV_ELEMS + PROJ_ELEMS + CMB_ELEMS + QKV_OC;
  prep_kernel<<<(prep_total + 255) / 256, 256, 0, stream>>>(
      qkv_w, proj_w, bias_table, rel_idx, mask, qkv_b, wq, wp, cmb, qb2);

  const int NB = 4096 / WB;
  const long ngran = (long)Mrows * 48;
  for (int b = 0; b < NB; ++b) {
    convx_kernel<<<(int)((ngran + 255) / 256), 256, 0, stream>>>(
        x + (size_t)b * Mrows * 384, xsw, ngran);
    gemm128<1><<<NRB * 9, 256, 0, stream>>>(xsw, wq, qb2, (void*)qkv,
                                            Mrows, 1152, 9);
    attn_kernel<<<WB, 512, 0, stream>>>(qkv, cmb, xsw, b * WB);
    gemm128<0><<<NRB * 3, 256, 0, stream>>>(xsw, wp, proj_b,
        (void*)(out + (size_t)b * Mrows * 384), Mrows, 384, 3);
  }
}